// Round 9
// baseline (1045.518 us; speedup 1.0000x reference)
//
#include <hip/hip_runtime.h>
#include <math.h>

// ComplexPolarTransformerBeta — round 9: cheap barriers + gemm pipelining.
// vs R8 (983us, spill-free, 1 block/CU, 4 waves, ~80% stall):
//  * All __syncthreads() -> lgkmcnt(0)-only s_barrier (inter-wave deps are LDS
//    only). Global weight loads stay in flight across barriers (AITER-style
//    "never vmcnt(0)").
//  * gemm kb-loops prefetch next-kb A-operands before the MFMAs of kb.
//  * softmax: fused online max+sum -> 1 barrier instead of 2.
// Numerics unchanged (split-3 bf16 hi/lo everywhere).

typedef __attribute__((ext_vector_type(8)))  short s16x8;
typedef __attribute__((ext_vector_type(16))) float f32x16;

#define STR  136      // LDS row stride (shorts): 128 data + 8 pad
#define LOFS 17408    // lo-plane offset within a region (shorts)
#define MFMA(a, b, c) __builtin_amdgcn_mfma_f32_32x32x16_bf16(a, b, c, 0, 0, 0)
#define ROWP(reg) (((reg) & 3) + (((reg) >> 2) << 3) + (h5 << 2))
// LDS-only barrier: don't drain vmcnt (global weight loads keep flying).
#define BAR() asm volatile("s_waitcnt lgkmcnt(0)\n\ts_barrier" ::: "memory")

__device__ __forceinline__ unsigned short bfhi(float x) {
  unsigned u = __float_as_uint(x);
  return (unsigned short)((u + 0x7FFFu + ((u >> 16) & 1u)) >> 16);
}
__device__ __forceinline__ float bf2f(unsigned short h) {
  return __uint_as_float(((unsigned)h) << 16);
}

// Stage one C-layout tile into S[row][colbase + 8q + 4h5] as bf16 hi/lo (b64).
__device__ __forceinline__ void stageB64(short* SH, const f32x16& acc, int row,
                                         int colbase, int h5, float scl) {
  #pragma unroll
  for (int q = 0; q < 4; ++q) {
    int col = colbase + 8 * q + 4 * h5;
    float v0 = acc[4*q+0] * scl, v1 = acc[4*q+1] * scl;
    float v2 = acc[4*q+2] * scl, v3 = acc[4*q+3] * scl;
    unsigned short h0 = bfhi(v0), h1 = bfhi(v1), h2 = bfhi(v2), h3 = bfhi(v3);
    *(short4*)(SH + row * STR + col) = make_short4((short)h0,(short)h1,(short)h2,(short)h3);
    *(short4*)(SH + LOFS + row * STR + col) =
        make_short4((short)bfhi(v0 - bf2f(h0)), (short)bfhi(v1 - bf2f(h1)),
                    (short)bfhi(v2 - bf2f(h2)), (short)bfhi(v3 - bf2f(h3)));
  }
}

// acc[tt] += Wfrag(m-tile)^ * B(LDS rows 32tt+l31).  A-prefetch pipelined.
__device__ __forceinline__ void gemmTW4(f32x16* acc, const short* W, const short* BH,
                                        int mtile, int kbN, int l31, int h5, int lane) {
  const short* wp0 = W + ((size_t)(mtile * 8) * 64 + lane) * 8;
  s16x8 ah = *(const s16x8*)wp0;
  s16x8 al = *(const s16x8*)(wp0 + 32768);
  #pragma unroll 1
  for (int kb = 0; kb < kbN; ++kb) {
    s16x8 nah, nal;
    if (kb + 1 < kbN) {
      const short* wpn = wp0 + (kb + 1) * 512;
      nah = *(const s16x8*)wpn;
      nal = *(const s16x8*)(wpn + 32768);
    }
    int k0 = kb * 16 + 8 * h5;
    #pragma unroll
    for (int tt = 0; tt < 4; ++tt) {
      int brow = 32 * tt + l31;
      s16x8 bh = *(const s16x8*)(BH + brow * STR + k0);
      s16x8 bl = *(const s16x8*)(BH + LOFS + brow * STR + k0);
      acc[tt] = MFMA(ah, bh, acc[tt]);
      acc[tt] = MFMA(ah, bl, acc[tt]);
      acc[tt] = MFMA(al, bh, acc[tt]);
    }
    ah = nah; al = nal;
  }
}

// acc[tt] += A(LDS rows mblk+l31) * Wfrag(n-tile=tt).  A-prefetch pipelined.
__device__ __forceinline__ void gemmNW4(f32x16* acc, const short* AH, const short* W,
                                        int mblk, int l31, int h5, int lane) {
  const short* ap = AH + (mblk + l31) * STR + 8 * h5;
  s16x8 ah = *(const s16x8*)ap;
  s16x8 al = *(const s16x8*)(ap + LOFS);
  #pragma unroll 1
  for (int kb = 0; kb < 8; ++kb) {
    s16x8 nah, nal;
    if (kb < 7) {
      nah = *(const s16x8*)(ap + (kb + 1) * 16);
      nal = *(const s16x8*)(ap + LOFS + (kb + 1) * 16);
    }
    #pragma unroll
    for (int tt = 0; tt < 4; ++tt) {
      const short* wp = W + ((size_t)((tt * 8 + kb) * 64 + lane)) * 8;
      s16x8 bh = *(const s16x8*)wp;
      s16x8 bl = *(const s16x8*)(wp + 32768);
      acc[tt] = MFMA(ah, bh, acc[tt]);
      acc[tt] = MFMA(ah, bl, acc[tt]);
      acc[tt] = MFMA(al, bh, acc[tt]);
    }
    ah = nah; al = nal;
  }
}

// acc[tt] += A(LDS rows mblk+l31) * B(LDS rows 32tt+l31)^T.  A-prefetch pipelined.
__device__ __forceinline__ void gemmLL4(f32x16* acc, const short* AH, const short* BH,
                                        int mblk, int l31, int h5) {
  const short* ap = AH + (mblk + l31) * STR + 8 * h5;
  s16x8 ah = *(const s16x8*)ap;
  s16x8 al = *(const s16x8*)(ap + LOFS);
  #pragma unroll 1
  for (int kb = 0; kb < 8; ++kb) {
    s16x8 nah, nal;
    if (kb < 7) {
      nah = *(const s16x8*)(ap + (kb + 1) * 16);
      nal = *(const s16x8*)(ap + LOFS + (kb + 1) * 16);
    }
    int k0 = kb * 16 + 8 * h5;
    #pragma unroll
    for (int tt = 0; tt < 4; ++tt) {
      int brow = 32 * tt + l31;
      s16x8 bh = *(const s16x8*)(BH + brow * STR + k0);
      s16x8 bl = *(const s16x8*)(BH + LOFS + brow * STR + k0);
      acc[tt] = MFMA(ah, bh, acc[tt]);
      acc[tt] = MFMA(ah, bl, acc[tt]);
      acc[tt] = MFMA(al, bh, acc[tt]);
    }
    ah = nah; al = nal;
  }
}

// ---------------- weight preprocessing: fp32 [k][h] -> frag-ordered bf16 hi/lo ----
__global__ __launch_bounds__(512)
void prep_kernel(const float* __restrict__ Wq, const float* __restrict__ Wk,
                 const float* __restrict__ Wvm, const float* __restrict__ Wvp,
                 const float* __restrict__ rp_W,
                 const float* __restrict__ emb_Wm, const float* __restrict__ emb_Wp,
                 short* __restrict__ ws) {
  int mid = blockIdx.x >> 2, hblk = blockIdx.x & 3;
  int kb = threadIdx.x >> 6, lane = threadIdx.x & 63;
  const float* src;
  int krows = 128;
  if (mid < 4)        src = Wq  + mid * 16384;
  else if (mid < 8)   src = Wk  + (mid - 4) * 16384;
  else if (mid < 12)  src = Wvm + (mid - 8) * 16384;
  else if (mid < 16)  src = Wvp + (mid - 12) * 16384;
  else if (mid == 16) src = rp_W;
  else if (mid == 17) src = rp_W + 16384;
  else if (mid == 18) { src = emb_Wm; krows = 19; }
  else                { src = emb_Wp; krows = 19; }
  int h = hblk * 32 + (lane & 31);
  int kbase = kb * 16 + ((lane >> 5) << 3);
  s16x8 H, L;
  #pragma unroll
  for (int j = 0; j < 8; ++j) {
    int k = kbase + j;
    float v = (k < krows) ? src[(size_t)k * 128 + h] : 0.f;
    unsigned short hi = bfhi(v);
    H[j] = (short)hi;
    L[j] = (short)bfhi(v - bf2f(hi));
  }
  short* dst = ws + (size_t)mid * 65536 + ((hblk * 8 + kb) * 64 + lane) * 8;
  *(s16x8*)dst = H;
  *(s16x8*)(dst + 32768) = L;
}

// ---------------- main kernel ----------------
__global__ __launch_bounds__(256, 2)
void cpt_kernel(const float* __restrict__ atom_types,
                const float* __restrict__ coords,
                const int*   __restrict__ edge_index,
                const float* __restrict__ edge_attr,
                const float* __restrict__ emb_bm, const float* __restrict__ emb_bp,
                const float* __restrict__ bq, const float* __restrict__ bk,
                const float* __restrict__ bvm, const float* __restrict__ bvp,
                const float* __restrict__ We,  const float* __restrict__ be,
                const float* __restrict__ dist_scale,
                const float* __restrict__ ln_g, const float* __restrict__ ln_b,
                const float* __restrict__ rp_b,
                const float* __restrict__ h1_W, const float* __restrict__ h1_b,
                const float* __restrict__ h2_W, const float* __restrict__ h2_b,
                const short* __restrict__ wpre,
                float* __restrict__ out)
{
  __shared__ __align__(16) short R1s[34816];
  __shared__ __align__(16) short R2s[34816];
  __shared__ float Pf[4096];     // bias quarter-matrix [128][32], col ^= (i&31)
  __shared__ float SCa[512];
  __shared__ float SCb[512];

  const int t = threadIdx.x, b = blockIdx.x;
  const int w = t >> 6, lane = t & 63, l31 = lane & 31, h5 = lane >> 5;
  const int mblk = w << 5;
  const float scale = 0.08838834764831845f;  // 1/sqrt(128)

  // ---- stage x (atom_types||coords, k padded to 32) into R1 as bf16 hi/lo ----
  if (t < 128) {
    const float* xr = atom_types + ((size_t)b * 128 + t) * 16;
    const float* cr = coords + ((size_t)b * 128 + t) * 3;
    float xv[19];
    float4 a0 = *(const float4*)xr,       a1 = *(const float4*)(xr + 4);
    float4 a2 = *(const float4*)(xr + 8), a3 = *(const float4*)(xr + 12);
    xv[0]=a0.x; xv[1]=a0.y; xv[2]=a0.z; xv[3]=a0.w;
    xv[4]=a1.x; xv[5]=a1.y; xv[6]=a1.z; xv[7]=a1.w;
    xv[8]=a2.x; xv[9]=a2.y; xv[10]=a2.z; xv[11]=a2.w;
    xv[12]=a3.x; xv[13]=a3.y; xv[14]=a3.z; xv[15]=a3.w;
    xv[16]=cr[0]; xv[17]=cr[1]; xv[18]=cr[2];
    #pragma unroll
    for (int k = 0; k < 32; ++k) {
      float v = (k < 19) ? xv[k] : 0.f;
      unsigned short hh = bfhi(v);
      R1s[t * STR + k] = (short)hh;
      R1s[LOFS + t * STR + k] = (short)bfhi(v - bf2f(hh));
    }
  }
  BAR();

  // ---- embedding via MFMA: magT/phT (TRANSPOSED: h=32w+ROWP(reg), a=32tt+l31) ----
  f32x16 magT[4], phT[4];
  {
    #pragma unroll
    for (int reg = 0; reg < 16; ++reg) {
      float bm = emb_bm[32 * w + ROWP(reg)];
      float bp = emb_bp[32 * w + ROWP(reg)];
      #pragma unroll
      for (int tt = 0; tt < 4; ++tt) { magT[tt][reg] = bm; phT[tt][reg] = bp; }
    }
    gemmTW4(magT, wpre + (size_t)18 * 65536, R1s, w, 2, l31, h5, lane);
    gemmTW4(phT,  wpre + (size_t)19 * 65536, R1s, w, 2, l31, h5, lane);
  }

  // ---- layers ----
  for (int l = 0; l < 4; ++l) {
    const short* wqP  = wpre + (size_t)l * 65536;
    const short* wkP  = wpre + (size_t)(4 + l) * 65536;
    const short* wvmP = wpre + (size_t)(8 + l) * 65536;
    const short* wvpP = wpre + (size_t)(12 + l) * 65536;

    BAR();                                           // prior readers done
    #pragma unroll
    for (int tt = 0; tt < 4; ++tt)
      stageB64(R1s, magT[tt], 32 * tt + l31, mblk, h5, 1.f);   // mag[a][h] -> R1
    BAR();

    // Q^T (D[h][i]) -> R2 scaled; then K^T (D[h][j]) held in accK
    {
      f32x16 accQ[4];
      #pragma unroll
      for (int reg = 0; reg < 16; ++reg) {
        float bv = bq[l * 128 + 32 * w + ROWP(reg)];
        #pragma unroll
        for (int tt = 0; tt < 4; ++tt) accQ[tt][reg] = bv;
      }
      gemmTW4(accQ, wqP, R1s, w, 8, l31, h5, lane);
      #pragma unroll
      for (int tt = 0; tt < 4; ++tt)
        stageB64(R2s, accQ[tt], 32 * tt + l31, mblk, h5, scale);  // Qs[i][h] -> R2
    }
    f32x16 accK[4];
    #pragma unroll
    for (int reg = 0; reg < 16; ++reg) {
      float bv = bk[l * 128 + 32 * w + ROWP(reg)];
      #pragma unroll
      for (int tt = 0; tt < 4; ++tt) accK[tt][reg] = bv;
    }
    gemmTW4(accK, wkP, R1s, w, 8, l31, h5, lane);
    BAR();                                           // all mag reads done
    #pragma unroll
    for (int tt = 0; tt < 4; ++tt)
      stageB64(R1s, accK[tt], 32 * tt + l31, mblk, h5, 1.f);    // K[j][h] -> R1
    BAR();

    // edge bias -> accS via quarter-buffer passes (accS: m=j=32w+ROWP, n=i=32tt+l31)
    f32x16 accS[4];
    {
      int e0i[4], e1i[4]; float ebv[4];
      float w0 = We[l*4], w1 = We[l*4+1], w2 = We[l*4+2], w3 = We[l*4+3];
      float bel = be[l], dsl = dist_scale[l];
      #pragma unroll
      for (int k = 0; k < 4; ++k) {
        int e = t + 256 * k;
        e0i[k] = edge_index[(size_t)b * 2048 + e];
        e1i[k] = edge_index[(size_t)b * 2048 + 1024 + e];
        float4 ea = *(const float4*)(edge_attr + ((size_t)b * 1024 + e) * 4);
        ebv[k] = ea.x*w0 + ea.y*w1 + ea.z*w2 + ea.w*w3 + bel + dsl*ea.x;
      }
      #pragma unroll 1
      for (int p = 0; p < 4; ++p) {
        #pragma unroll
        for (int k = 0; k < 16; ++k) Pf[t + 256 * k] = 0.f;
        BAR();
        #pragma unroll
        for (int k = 0; k < 4; ++k)
          if ((e1i[k] >> 5) == p)
            atomicAdd(&Pf[e0i[k] * 32 + ((e1i[k] & 31) ^ (e0i[k] & 31))], ebv[k]);
        BAR();
        if (w == p) {
          #pragma unroll
          for (int tt = 0; tt < 4; ++tt) {
            int i = 32 * tt + l31;
            #pragma unroll
            for (int reg = 0; reg < 16; ++reg)
              accS[tt][reg] = Pf[i * 32 + (ROWP(reg) ^ l31)];
          }
        }
        BAR();
      }
    }

    // scoresT[j][i] = K @ Qs^T + bias
    gemmLL4(accS, R1s, R2s, mblk, l31, h5);

    // fused online softmax over j: one barrier
    float mloc[4];
    #pragma unroll
    for (int tt = 0; tt < 4; ++tt) {
      float m = accS[tt][0];
      #pragma unroll
      for (int reg = 1; reg < 16; ++reg) m = fmaxf(m, accS[tt][reg]);
      m = fmaxf(m, __shfl_xor(m, 32));
      float s = 0.f;
      #pragma unroll
      for (int reg = 0; reg < 16; ++reg) {
        float e = __expf(accS[tt][reg] - m);
        accS[tt][reg] = e; s += e;
      }
      s += __shfl_xor(s, 32);
      mloc[tt] = m;
      if (h5 == 0) { SCa[w * 128 + 32 * tt + l31] = m; SCb[w * 128 + 32 * tt + l31] = s; }
    }
    BAR();
    #pragma unroll
    for (int tt = 0; tt < 4; ++tt) {
      int i = 32 * tt + l31;
      float m0 = SCa[i], m1 = SCa[128 + i], m2 = SCa[256 + i], m3 = SCa[384 + i];
      float mg = fmaxf(fmaxf(m0, m1), fmaxf(m2, m3));
      float sg = SCb[i] * __expf(m0 - mg) + SCb[128 + i] * __expf(m1 - mg) +
                 SCb[256 + i] * __expf(m2 - mg) + SCb[384 + i] * __expf(m3 - mg);
      float f = __expf(mloc[tt] - mg) / sg;
      #pragma unroll
      for (int reg = 0; reg < 16; ++reg) accS[tt][reg] *= f;
    }
    #pragma unroll
    for (int tt = 0; tt < 4; ++tt)
      stageB64(R2s, accS[tt], 32 * tt + l31, mblk, h5, 1.f);    // attn[i][j] -> R2
    #pragma unroll
    for (int tt = 0; tt < 4; ++tt)
      stageB64(R1s, magT[tt], 32 * tt + l31, mblk, h5, 1.f);    // mag[a][h] -> R1
    BAR();

    // vm = mag @ Wvm (normal, D[j][h]); staged as vmT[h][j]
    {
      f32x16 accVM[4];
      #pragma unroll
      for (int tt = 0; tt < 4; ++tt) {
        float bv = bvm[l * 128 + 32 * tt + l31];
        #pragma unroll
        for (int reg = 0; reg < 16; ++reg) accVM[tt][reg] = bv;
      }
      gemmNW4(accVM, R1s, wvmP, mblk, l31, h5, lane);
      BAR();                                         // all mag reads done
      #pragma unroll
      for (int tt = 0; tt < 4; ++tt)
        stageB64(R1s, accVM[tt], 32 * tt + l31, mblk, h5, 1.f); // vmT[h][j] -> R1
      BAR();
    }

    // new_mag^T = vm^T @ attn^T + mag^T
    f32x16 accM[4];
    #pragma unroll
    for (int tt = 0; tt < 4; ++tt) accM[tt] = magT[tt];
    gemmLL4(accM, R1s, R2s, mblk, l31, h5);

    // LayerNorm over h
    {
      #pragma unroll
      for (int tt = 0; tt < 4; ++tt) {
        float s = 0.f, q = 0.f;
        #pragma unroll
        for (int reg = 0; reg < 16; ++reg) { float v = accM[tt][reg]; s += v; q += v*v; }
        s += __shfl_xor(s, 32); q += __shfl_xor(q, 32);
        if (h5 == 0) { SCa[w * 128 + 32 * tt + l31] = s; SCb[w * 128 + 32 * tt + l31] = q; }
      }
      BAR();
      #pragma unroll
      for (int reg = 0; reg < 16; ++reg) {
        float gv = ln_g[l * 128 + 32 * w + ROWP(reg)];
        float bv = ln_b[l * 128 + 32 * w + ROWP(reg)];
        #pragma unroll
        for (int tt = 0; tt < 4; ++tt) {
          int i = 32 * tt + l31;
          float s = SCa[i] + SCa[128 + i] + SCa[256 + i] + SCa[384 + i];
          float q = SCb[i] + SCb[128 + i] + SCb[256 + i] + SCb[384 + i];
          float mu = s * (1.f / 128.f);
          float var = q * (1.f / 128.f) - mu * mu;
          float inv = 1.f / sqrtf(var + 1e-5f);
          magT[tt][reg] = gv * ((accM[tt][reg] - mu) * inv) + bv;
        }
      }
    }
    #pragma unroll
    for (int tt = 0; tt < 4; ++tt)
      stageB64(R1s, phT[tt], 32 * tt + l31, mblk, h5, 1.f);     // ph[a][h] -> R1
    BAR();

    // vp = ph @ Wvp (normal); staged as vpT[h][j]
    {
      f32x16 accV[4];
      #pragma unroll
      for (int tt = 0; tt < 4; ++tt) {
        float bv = bvp[l * 128 + 32 * tt + l31];
        #pragma unroll
        for (int reg = 0; reg < 16; ++reg) accV[tt][reg] = bv;
      }
      gemmNW4(accV, R1s, wvpP, mblk, l31, h5, lane);
      BAR();                                         // all ph reads done
      #pragma unroll
      for (int tt = 0; tt < 4; ++tt)
        stageB64(R1s, accV[tt], 32 * tt + l31, mblk, h5, 1.f);  // vpT[h][j] -> R1
      BAR();
    }

    // new_ph^T = vp^T @ attn^T + ph^T
    f32x16 accP[4];
    #pragma unroll
    for (int tt = 0; tt < 4; ++tt) accP[tt] = phT[tt];
    gemmLL4(accP, R1s, R2s, mblk, l31, h5);
    #pragma unroll
    for (int tt = 0; tt < 4; ++tt) phT[tt] = accP[tt];
  } // layers

  // ---- real/imag -> RealProjection (transposed accR: hout=32w+ROWP, a=32tt+l31) ----
  f32x16 reT[4], imT[4];
  #pragma unroll
  for (int tt = 0; tt < 4; ++tt)
    #pragma unroll
    for (int reg = 0; reg < 16; ++reg) {
      float s_, c_;
      __sincosf(phT[tt][reg], &s_, &c_);
      reT[tt][reg] = magT[tt][reg] * c_;
      imT[tt][reg] = magT[tt][reg] * s_;
    }
  BAR();
  #pragma unroll
  for (int tt = 0; tt < 4; ++tt) {
    stageB64(R1s, reT[tt], 32 * tt + l31, mblk, h5, 1.f);   // re[a][h] -> R1
    stageB64(R2s, imT[tt], 32 * tt + l31, mblk, h5, 1.f);   // im[a][h] -> R2
  }
  BAR();
  f32x16 accR[4];
  #pragma unroll
  for (int reg = 0; reg < 16; ++reg) {
    float bv = rp_b[32 * w + ROWP(reg)];
    #pragma unroll
    for (int tt = 0; tt < 4; ++tt) accR[tt][reg] = bv;
  }
  gemmTW4(accR, wpre + (size_t)16 * 65536, R1s, w, 8, l31, h5, lane);  // rpA^T @ re^T
  gemmTW4(accR, wpre + (size_t)17 * 65536, R2s, w, 8, l31, h5, lane);  // rpB^T @ im^T

  // ---- pooling: column sum over atoms a (tt in-thread + l31 shfl) ----
  {
    float cs[16];
    #pragma unroll
    for (int reg = 0; reg < 16; ++reg) {
      float s = accR[0][reg] + accR[1][reg] + accR[2][reg] + accR[3][reg];
      s += __shfl_xor(s, 16); s += __shfl_xor(s, 8);
      s += __shfl_xor(s, 4);  s += __shfl_xor(s, 2); s += __shfl_xor(s, 1);
      cs[reg] = s;
    }
    if (l31 == 0) {
      #pragma unroll
      for (int reg = 0; reg < 16; ++reg) SCa[32 * w + ROWP(reg)] = cs[reg];
    }
  }
  BAR();
  if (t < 128) {
    float acc = h1_b[t];
    for (int i = 0; i < 128; ++i) {
      float c = SCa[i];
      acc += c * (h1_W[(size_t)i * 128 + t] * (1.f / 128.f) +
                  h1_W[(size_t)(128 + i) * 128 + t]);
    }
    float hv = acc / (1.f + __expf(-acc));   // SiLU
    SCb[t] = hv * h2_W[t];
  }
  BAR();
  if (t < 64) {
    float s2 = SCb[t] + SCb[64 + t];
    #pragma unroll
    for (int off = 32; off >= 1; off >>= 1) s2 += __shfl_xor(s2, off);
    if (t == 0) out[b] = s2 + h2_b[0];
  }
}

extern "C" void kernel_launch(void* const* d_in, const int* in_sizes, int n_in,
                              void* d_out, int out_size, void* d_ws, size_t ws_size,
                              hipStream_t stream) {
  const float* atom_types = (const float*)d_in[0];
  const float* coords     = (const float*)d_in[1];
  const int*   edge_index = (const int*)  d_in[2];
  const float* edge_attr  = (const float*)d_in[3];
  const float* emb_Wm = (const float*)d_in[4];
  const float* emb_bm = (const float*)d_in[5];
  const float* emb_Wp = (const float*)d_in[6];
  const float* emb_bp = (const float*)d_in[7];
  const float* Wq  = (const float*)d_in[8];
  const float* bq  = (const float*)d_in[9];
  const float* Wk  = (const float*)d_in[10];
  const float* bk  = (const float*)d_in[11];
  const float* Wvm = (const float*)d_in[12];
  const float* bvm = (const float*)d_in[13];
  const float* Wvp = (const float*)d_in[14];
  const float* bvp = (const float*)d_in[15];
  const float* We  = (const float*)d_in[16];
  const float* be  = (const float*)d_in[17];
  const float* dist_scale = (const float*)d_in[18];
  const float* ln_g = (const float*)d_in[19];
  const float* ln_b = (const float*)d_in[20];
  const float* rp_W = (const float*)d_in[21];
  const float* rp_b = (const float*)d_in[22];
  const float* h1_W = (const float*)d_in[23];
  const float* h1_b = (const float*)d_in[24];
  const float* h2_W = (const float*)d_in[25];
  const float* h2_b = (const float*)d_in[26];
  float* out = (float*)d_out;
  short* wpre = (short*)d_ws;   // 20 matrices * 131072 B = 2.62 MB

  hipLaunchKernelGGL(prep_kernel, dim3(80), dim3(512), 0, stream,
                     Wq, Wk, Wvm, Wvp, rp_W, emb_Wm, emb_Wp, wpre);
  hipLaunchKernelGGL(cpt_kernel, dim3(1024), dim3(256), 0, stream,
                     atom_types, coords, edge_index, edge_attr,
                     emb_bm, emb_bp,
                     bq, bk, bvm, bvp,
                     We, be, dist_scale, ln_g, ln_b,
                     rp_b, h1_W, h1_b, h2_W, h2_b,
                     (const short*)wpre, out);
}